// Round 4
// baseline (4469.340 us; speedup 1.0000x reference)
//
#include <hip/hip_runtime.h>

constexpr int NROW  = 16384;   // B*T
constexpr int DIM   = 512;
constexpr int KCODE = 8192;

constexpr int RB   = 128;   // rows per block
constexpr int CB   = 1024;  // codes per block (split-K: KCODE/CB = 8 splits)
constexpr int TCT  = 128;   // codes per LDS tile
constexpr int DCH  = 32;    // depth chunk
constexpr int LS   = 36;    // LDS stride (pad: broadcast-friendly, bank-clean)

// d_out offsets (in floats)
constexpr size_t Q_OFF = 0;          // quantized_st [16,1024,512]
constexpr size_t T_OFF = 8388608;    // targets [16,1024]
constexpr size_t L_OFF = 8404992;    // extra_losses scalar
constexpr size_t E_OFF = 8404993;    // new_embeddings [8192,512]
constexpr size_t C_OFF = 12599297;   // new_cs [8192]
constexpr size_t W_OFF = 12607489;   // new_w [8192,512]

// ws offsets (bytes)
constexpr size_t WS_KEYS   = 0;        // u64[NROW]
constexpr size_t WS_CSIZE  = 131072;   // float[KCODE]
constexpr size_t WS_COMMIT = 163840;   // float
constexpr size_t WS_CSSUM  = 163844;   // float
constexpr size_t WS_XNORM  = 196608;   // float[NROW]
constexpr size_t WS_ENORM  = 262144;   // float[KCODE]
constexpr size_t WS_ESUM   = 327680;   // float[KCODE*DIM]
constexpr size_t WS_NEEDED = WS_ESUM + (size_t)KCODE * DIM * 4;

// ---------------- kernel 1: row sum-of-squares, numpy pairwise order --------
__global__ void rownorm_kernel(const float* __restrict__ src, float* __restrict__ dst) {
    #pragma clang fp contract(off)
    __shared__ float s[4][DIM];
    __shared__ float rr[4][32];
    const int wave = threadIdx.x >> 6, lane = threadIdx.x & 63;
    const int row = blockIdx.x * 4 + wave;
    const float4* p = (const float4*)(src + (size_t)row * DIM);
    float4 v0 = p[lane];
    float4 v1 = p[lane + 64];
    *(float4*)&s[wave][lane * 4] = v0;
    *(float4*)&s[wave][(lane + 64) * 4] = v1;
    __syncthreads();
    if (lane < 32) {
        const int b = lane >> 3, j = lane & 7;
        const float* q = &s[wave][b * 128 + j];
        float x = q[0];
        float r = x * x;
        for (int t = 1; t < 16; ++t) {
            float y = q[8 * t];
            float py = y * y;
            r = r + py;
        }
        rr[wave][lane] = r;
    }
    __syncthreads();
    if (lane == 0) {
        const float* R = rr[wave];
        float B0 = ((R[0] + R[1]) + (R[2] + R[3])) + ((R[4] + R[5]) + (R[6] + R[7]));
        float B1 = ((R[8] + R[9]) + (R[10] + R[11])) + ((R[12] + R[13]) + (R[14] + R[15]));
        float B2 = ((R[16] + R[17]) + (R[18] + R[19])) + ((R[20] + R[21]) + (R[22] + R[23]));
        float B3 = ((R[24] + R[25]) + (R[26] + R[27])) + ((R[28] + R[29]) + (R[30] + R[31]));
        dst[row] = (B0 + B1) + (B2 + B3);
    }
}

// ---------------- kernel 2: argmin, register-prefetch double-buffered -------
__launch_bounds__(256, 3)
__global__ void argmin_kernel(const float* __restrict__ feat,
                              const float* __restrict__ emb,
                              const float* __restrict__ xnorm,
                              const float* __restrict__ enorm,
                              unsigned long long* __restrict__ keys) {
    __shared__ float As[RB][LS];    // 18 KB
    __shared__ float Bs[TCT][LS];   // 18 KB

    const int tid = threadIdx.x;
    const int tx = tid & 15, ty = tid >> 4;
    const int rb = blockIdx.x & 127;
    const int ks = blockIdx.x >> 7;
    const int row0 = rb * RB;
    const int code0 = ks * CB;

    // staging coords for this thread (4 float4 each for A and B per chunk)
    const int sr[4] = { tid >> 3, (256 + tid) >> 3, (512 + tid) >> 3, (768 + tid) >> 3 };
    const int sj = (tid & 7) * 4;

    float xn[8];
    #pragma unroll
    for (int i = 0; i < 8; ++i) xn[i] = xnorm[row0 + ty + 16 * i];

    float bestv[8];
    int   besti[8];
    #pragma unroll
    for (int i = 0; i < 8; ++i) { bestv[i] = 3.4e38f; besti[i] = 0; }

    // prefetch chunk (ct=code0, d0=0) into registers
    float4 pa[4], pb[4];
    #pragma unroll
    for (int p = 0; p < 4; ++p) {
        pa[p] = *(const float4*)&feat[(size_t)(row0 + sr[p]) * DIM + sj];
        pb[p] = *(const float4*)&emb[(size_t)(code0 + sr[p]) * DIM + sj];
    }

    for (int ct = code0; ct < code0 + CB; ct += TCT) {
        // prefetch this tile's enorm values (latency hidden by tile compute)
        float en8[8];
        #pragma unroll
        for (int u = 0; u < 8; ++u) en8[u] = enorm[ct + tx + 16 * u];

        float acc[8][8] = {};
        for (int d0 = 0; d0 < DIM; d0 += DCH) {
            __syncthreads();   // prior compute done reading LDS
            #pragma unroll
            for (int p = 0; p < 4; ++p) {
                *(float4*)&As[sr[p]][sj] = pa[p];
                *(float4*)&Bs[sr[p]][sj] = pb[p];
            }
            __syncthreads();
            // issue next chunk's global loads; they land during compute below
            int nd0 = d0 + DCH, nct = ct;
            if (nd0 == DIM) { nd0 = 0; nct += TCT; }
            if (nct < code0 + CB) {
                #pragma unroll
                for (int p = 0; p < 4; ++p) {
                    pa[p] = *(const float4*)&feat[(size_t)(row0 + sr[p]) * DIM + nd0 + sj];
                    pb[p] = *(const float4*)&emb[(size_t)(nct + sr[p]) * DIM + nd0 + sj];
                }
            }
            #pragma unroll
            for (int k4 = 0; k4 < DCH / 4; ++k4) {
                float4 a4[8];
                #pragma unroll
                for (int i = 0; i < 8; ++i)
                    a4[i] = *(const float4*)&As[ty + 16 * i][k4 * 4];
                #pragma unroll
                for (int u = 0; u < 8; ++u) {
                    float4 b4 = *(const float4*)&Bs[tx + 16 * u][k4 * 4];
                    #pragma unroll
                    for (int i = 0; i < 8; ++i) {
                        acc[i][u] = fmaf(a4[i].x, b4.x, acc[i][u]);   // k-ascending chain
                        acc[i][u] = fmaf(a4[i].y, b4.y, acc[i][u]);
                        acc[i][u] = fmaf(a4[i].z, b4.z, acc[i][u]);
                        acc[i][u] = fmaf(a4[i].w, b4.w, acc[i][u]);
                    }
                }
            }
        }
        #pragma unroll
        for (int u = 0; u < 8; ++u) {
            int code = ct + tx + 16 * u;
            #pragma unroll
            for (int i = 0; i < 8; ++i) {
                float t2 = fmaf(-2.0f, acc[i][u], xn[i]);
                float s = t2 + en8[u];
                if (s < bestv[i]) { bestv[i] = s; besti[i] = code; }
            }
        }
    }

    // per-row reduce over tx, then global atomicMin on sortable key
    __syncthreads();
    float* sval = &As[0][0];
    int*   sidx = (int*)&Bs[0][0];
    #pragma unroll
    for (int i = 0; i < 8; ++i) {
        int row = ty + 16 * i;
        sval[row * 17 + tx] = bestv[i];
        sidx[row * 17 + tx] = besti[i];
    }
    __syncthreads();
    if (tid < RB) {
        float bv = sval[tid * 17]; int bi = sidx[tid * 17];
        for (int t = 1; t < 16; ++t) {
            float v = sval[tid * 17 + t]; int ii = sidx[tid * 17 + t];
            if (v < bv || (v == bv && ii < bi)) { bv = v; bi = ii; }
        }
        unsigned int vb = __float_as_uint(bv);
        vb = (vb & 0x80000000u) ? ~vb : (vb | 0x80000000u);
        unsigned long long key = ((unsigned long long)vb << 32) | (unsigned int)bi;
        atomicMin(&keys[row0 + tid], key);
    }
}

// ---------------- kernel 3: gather + commitment + scatter-add ---------------
__global__ void gather_kernel(const float* __restrict__ feat,
                              const float* __restrict__ emb,
                              const unsigned long long* __restrict__ keys,
                              float* __restrict__ qout,
                              float* __restrict__ targets,
                              float* __restrict__ esum,
                              float* __restrict__ csize,
                              float* __restrict__ commit) {
    const int row = blockIdx.x;
    const int code = (int)(keys[row] & 0x7fffffffu);
    const int d = threadIdx.x * 2;
    float2 f = *(const float2*)&feat[(size_t)row * DIM + d];
    float2 q = *(const float2*)&emb[(size_t)code * DIM + d];
    float2 qst;
    qst.x = f.x + (q.x - f.x);
    qst.y = f.y + (q.y - f.y);
    *(float2*)&qout[(size_t)row * DIM + d] = qst;
    float dx = f.x - qst.x, dy = f.y - qst.y;
    float local = dx * dx + dy * dy;
    #pragma unroll
    for (int off = 32; off; off >>= 1) local += __shfl_down(local, off, 64);
    __shared__ float wsum[4];
    int lane = threadIdx.x & 63, wv = threadIdx.x >> 6;
    if (lane == 0) wsum[wv] = local;
    __syncthreads();
    if (threadIdx.x == 0) {
        atomicAdd(commit, wsum[0] + wsum[1] + wsum[2] + wsum[3]);
        atomicAdd(&csize[code], 1.0f);
        targets[row] = (float)code;
    }
    atomicAdd(&esum[(size_t)code * DIM + d], f.x);
    atomicAdd(&esum[(size_t)code * DIM + d + 1], f.y);
}

// ---------------- kernel 4: new_cs + sum(new_cs) + loss ---------------------
__global__ void newcs_kernel(const float* __restrict__ ema_cs,
                             const float* __restrict__ csize,
                             float* __restrict__ out_cs,
                             float* __restrict__ cs_sum,
                             const float* __restrict__ commit,
                             float* __restrict__ out_loss) {
    int i = blockIdx.x * 256 + threadIdx.x;
    float v = 0.99f * ema_cs[i] + 0.01f * csize[i];
    out_cs[i] = v;
    float s = v;
    #pragma unroll
    for (int off = 32; off; off >>= 1) s += __shfl_down(s, off, 64);
    __shared__ float wsum[4];
    int lane = threadIdx.x & 63, wv = threadIdx.x >> 6;
    if (lane == 0) wsum[wv] = s;
    __syncthreads();
    if (threadIdx.x == 0)
        atomicAdd(cs_sum, wsum[0] + wsum[1] + wsum[2] + wsum[3]);
    if (blockIdx.x == 0 && threadIdx.x == 0)
        out_loss[0] = 0.25f * commit[0] / 8388608.0f;
}

// ---------------- kernel 5: new_w + new_embeddings --------------------------
__global__ void final_kernel(const float* __restrict__ ema_w,
                             const float* __restrict__ esum,
                             const float* __restrict__ new_cs,
                             const float* __restrict__ cs_sum,
                             float* __restrict__ out_w,
                             float* __restrict__ out_emb) {
    size_t i4 = ((size_t)blockIdx.x * 256 + threadIdx.x) * 4;
    int k = (int)(i4 >> 9);
    float S = cs_sum[0] + (float)KCODE * 1e-5f;
    float4 es = *(const float4*)&esum[i4];
    float4 ew = *(const float4*)&ema_w[i4];
    float w0 = 0.99f * ew.x + 0.01f * es.x;
    float w1 = 0.99f * ew.y + 0.01f * es.y;
    float w2 = 0.99f * ew.z + 0.01f * es.z;
    float w3 = 0.99f * ew.w + 0.01f * es.w;
    out_w[i4 + 0] = w0; out_w[i4 + 1] = w1; out_w[i4 + 2] = w2; out_w[i4 + 3] = w3;
    float scale = S / (new_cs[k] + 1e-5f);
    out_emb[i4 + 0] = w0 * scale; out_emb[i4 + 1] = w1 * scale;
    out_emb[i4 + 2] = w2 * scale; out_emb[i4 + 3] = w3 * scale;
}

// ---------------------------------------------------------------------------
extern "C" void kernel_launch(void* const* d_in, const int* in_sizes, int n_in,
                              void* d_out, int out_size, void* d_ws, size_t ws_size,
                              hipStream_t stream) {
    const float* feat   = (const float*)d_in[0];
    const float* emb    = (const float*)d_in[1];
    const float* ema_cs = (const float*)d_in[2];
    const float* ema_w  = (const float*)d_in[3];
    float* out = (float*)d_out;
    char* ws = (char*)d_ws;
    if (ws_size < WS_NEEDED) return;

    unsigned long long* keys = (unsigned long long*)(ws + WS_KEYS);
    float* csize  = (float*)(ws + WS_CSIZE);
    float* commit = (float*)(ws + WS_COMMIT);
    float* cssum  = (float*)(ws + WS_CSSUM);
    float* xnorm  = (float*)(ws + WS_XNORM);
    float* enorm  = (float*)(ws + WS_ENORM);
    float* esum   = (float*)(ws + WS_ESUM);

    hipMemsetAsync(ws + WS_KEYS, 0xFF, (size_t)NROW * 8, stream);
    hipMemsetAsync(ws + WS_CSIZE, 0, WS_CSSUM + 4 - WS_CSIZE, stream);
    hipMemsetAsync(ws + WS_ESUM, 0, (size_t)KCODE * DIM * 4, stream);

    rownorm_kernel<<<NROW / 4, 256, 0, stream>>>(feat, xnorm);
    rownorm_kernel<<<KCODE / 4, 256, 0, stream>>>(emb, enorm);
    argmin_kernel<<<(NROW / RB) * (KCODE / CB), 256, 0, stream>>>(feat, emb, xnorm, enorm, keys);
    gather_kernel<<<NROW, 256, 0, stream>>>(feat, emb, keys, out + Q_OFF, out + T_OFF,
                                            esum, csize, commit);
    newcs_kernel<<<KCODE / 256, 256, 0, stream>>>(ema_cs, csize, out + C_OFF, cssum, commit, out + L_OFF);
    final_kernel<<<KCODE * DIM / 1024, 256, 0, stream>>>(ema_w, esum, out + C_OFF, cssum,
                                                         out + W_OFF, out + E_OFF);
}

// Round 5
// 2063.621 us; speedup vs baseline: 2.1658x; 2.1658x over previous
//
#include <hip/hip_runtime.h>

constexpr int NROW  = 16384;   // B*T
constexpr int DIM   = 512;
constexpr int KCODE = 8192;

constexpr int RB   = 128;   // rows per block
constexpr int CB   = 1024;  // codes per block (split-K: 8 splits)
constexpr int TCT  = 128;   // codes per LDS tile
constexpr int DCH  = 32;    // depth chunk
constexpr int LS   = 36;    // LDS stride (bank-clean, verified round 3)

// d_out offsets (in floats)
constexpr size_t Q_OFF = 0;          // quantized_st [16,1024,512]
constexpr size_t T_OFF = 8388608;    // targets [16,1024]
constexpr size_t L_OFF = 8404992;    // extra_losses scalar
constexpr size_t E_OFF = 8404993;    // new_embeddings [8192,512]
constexpr size_t C_OFF = 12599297;   // new_cs [8192]
constexpr size_t W_OFF = 12607489;   // new_w [8192,512]

// ws offsets (bytes)
constexpr size_t WS_KEYS   = 0;        // u64[NROW]
constexpr size_t WS_CSIZE  = 131072;   // float[KCODE]
constexpr size_t WS_COMMIT = 163840;   // float
constexpr size_t WS_CSSUM  = 163844;   // float
constexpr size_t WS_XNORM  = 196608;   // float[NROW]
constexpr size_t WS_ENORM  = 262144;   // float[KCODE]
constexpr size_t WS_ESUM   = 327680;   // float[KCODE*DIM]
constexpr size_t WS_NEEDED = WS_ESUM + (size_t)KCODE * DIM * 4;

// ---------------- kernel 1: row sum-of-squares, numpy pairwise order --------
__global__ void rownorm_kernel(const float* __restrict__ src, float* __restrict__ dst) {
    #pragma clang fp contract(off)
    __shared__ float s[4][DIM];
    __shared__ float rr[4][32];
    const int wave = threadIdx.x >> 6, lane = threadIdx.x & 63;
    const int row = blockIdx.x * 4 + wave;
    const float4* p = (const float4*)(src + (size_t)row * DIM);
    float4 v0 = p[lane];
    float4 v1 = p[lane + 64];
    *(float4*)&s[wave][lane * 4] = v0;
    *(float4*)&s[wave][(lane + 64) * 4] = v1;
    __syncthreads();
    if (lane < 32) {
        const int b = lane >> 3, j = lane & 7;
        const float* q = &s[wave][b * 128 + j];
        float x = q[0];
        float r = x * x;
        for (int t = 1; t < 16; ++t) {
            float y = q[8 * t];
            float py = y * y;
            r = r + py;
        }
        rr[wave][lane] = r;
    }
    __syncthreads();
    if (lane == 0) {
        const float* R = rr[wave];
        float B0 = ((R[0] + R[1]) + (R[2] + R[3])) + ((R[4] + R[5]) + (R[6] + R[7]));
        float B1 = ((R[8] + R[9]) + (R[10] + R[11])) + ((R[12] + R[13]) + (R[14] + R[15]));
        float B2 = ((R[16] + R[17]) + (R[18] + R[19])) + ((R[20] + R[21]) + (R[22] + R[23]));
        float B3 = ((R[24] + R[25]) + (R[26] + R[27])) + ((R[28] + R[29]) + (R[30] + R[31]));
        dst[row] = (B0 + B1) + (B2 + B3);
    }
}

// ---------------- kernel 2: argmin, 512 thr, 4x8 micro, low reg pressure ----
__launch_bounds__(512, 4)
__global__ void argmin_kernel(const float* __restrict__ feat,
                              const float* __restrict__ emb,
                              const float* __restrict__ xnorm,
                              const float* __restrict__ enorm,
                              unsigned long long* __restrict__ keys) {
    __shared__ float As[RB][LS];    // 18 KB
    __shared__ float Bs[TCT][LS];   // 18 KB

    const int tid = threadIdx.x;
    const int tx = tid & 15;            // 16 code-cols, 8 codes each
    const int ty = tid >> 4;            // 32 row-groups, 4 rows each
    const int rb = blockIdx.x & 127;
    const int ks = blockIdx.x >> 7;
    const int row0 = rb * RB;
    const int code0 = ks * CB;

    // staging coords: 2 float4 each for A and B per chunk (1024 float4 total)
    const int sr0 = tid >> 3;           // rows 0..63
    const int sr1 = sr0 + 64;           // rows 64..127
    const int sj = (tid & 7) * 4;

    float xn[4];
    #pragma unroll
    for (int i = 0; i < 4; ++i) xn[i] = xnorm[row0 + ty + 32 * i];

    float bestv[4] = {3.4e38f, 3.4e38f, 3.4e38f, 3.4e38f};
    int   besti[4] = {0, 0, 0, 0};

    // prefetch first chunk (ct=code0, d0=0)
    float4 pa0 = *(const float4*)&feat[(size_t)(row0 + sr0) * DIM + sj];
    float4 pa1 = *(const float4*)&feat[(size_t)(row0 + sr1) * DIM + sj];
    float4 pb0 = *(const float4*)&emb[(size_t)(code0 + sr0) * DIM + sj];
    float4 pb1 = *(const float4*)&emb[(size_t)(code0 + sr1) * DIM + sj];

    for (int ct = code0; ct < code0 + CB; ct += TCT) {
        float acc[4][8] = {};
        for (int d0 = 0; d0 < DIM; d0 += DCH) {
            __syncthreads();
            *(float4*)&As[sr0][sj] = pa0;
            *(float4*)&As[sr1][sj] = pa1;
            *(float4*)&Bs[sr0][sj] = pb0;
            *(float4*)&Bs[sr1][sj] = pb1;
            __syncthreads();
            // issue next chunk's loads; land during compute below
            int nd0 = d0 + DCH, nct = ct;
            if (nd0 == DIM) { nd0 = 0; nct += TCT; }
            if (nct == code0 + CB) nct = code0;    // in-bounds wrap (redundant load)
            pa0 = *(const float4*)&feat[(size_t)(row0 + sr0) * DIM + nd0 + sj];
            pa1 = *(const float4*)&feat[(size_t)(row0 + sr1) * DIM + nd0 + sj];
            pb0 = *(const float4*)&emb[(size_t)(nct + sr0) * DIM + nd0 + sj];
            pb1 = *(const float4*)&emb[(size_t)(nct + sr1) * DIM + nd0 + sj];
            #pragma unroll
            for (int k4 = 0; k4 < DCH / 4; ++k4) {
                float4 a4[4];
                #pragma unroll
                for (int i = 0; i < 4; ++i)
                    a4[i] = *(const float4*)&As[ty + 32 * i][k4 * 4];
                #pragma unroll
                for (int u = 0; u < 8; ++u) {
                    float4 b4 = *(const float4*)&Bs[tx + 16 * u][k4 * 4];
                    #pragma unroll
                    for (int i = 0; i < 4; ++i) {
                        acc[i][u] = fmaf(a4[i].x, b4.x, acc[i][u]);   // k-ascending chain
                        acc[i][u] = fmaf(a4[i].y, b4.y, acc[i][u]);
                        acc[i][u] = fmaf(a4[i].z, b4.z, acc[i][u]);
                        acc[i][u] = fmaf(a4[i].w, b4.w, acc[i][u]);
                    }
                }
            }
        }
        #pragma unroll
        for (int u = 0; u < 8; ++u) {
            int code = ct + tx + 16 * u;
            float en = enorm[code];
            #pragma unroll
            for (int i = 0; i < 4; ++i) {
                float t2 = fmaf(-2.0f, acc[i][u], xn[i]);
                float s = t2 + en;
                if (s < bestv[i]) { bestv[i] = s; besti[i] = code; }
            }
        }
    }

    // per-row reduce over tx (16 candidates/row), then global atomicMin
    __syncthreads();
    float* sval = &As[0][0];          // [128][17] floats
    int*   sidx = (int*)&Bs[0][0];
    #pragma unroll
    for (int i = 0; i < 4; ++i) {
        int row = ty + 32 * i;
        sval[row * 17 + tx] = bestv[i];
        sidx[row * 17 + tx] = besti[i];
    }
    __syncthreads();
    if (tid < RB) {
        float bv = sval[tid * 17]; int bi = sidx[tid * 17];
        for (int t = 1; t < 16; ++t) {
            float v = sval[tid * 17 + t]; int ii = sidx[tid * 17 + t];
            if (v < bv || (v == bv && ii < bi)) { bv = v; bi = ii; }
        }
        unsigned int vb = __float_as_uint(bv);
        vb = (vb & 0x80000000u) ? ~vb : (vb | 0x80000000u);
        unsigned long long key = ((unsigned long long)vb << 32) | (unsigned int)bi;
        atomicMin(&keys[row0 + tid], key);
    }
}

// ---------------- kernel 3: gather + commitment + scatter-add ---------------
__global__ void gather_kernel(const float* __restrict__ feat,
                              const float* __restrict__ emb,
                              const unsigned long long* __restrict__ keys,
                              float* __restrict__ qout,
                              float* __restrict__ targets,
                              float* __restrict__ esum,
                              float* __restrict__ csize,
                              float* __restrict__ commit) {
    const int row = blockIdx.x;
    const int code = (int)(keys[row] & 0x7fffffffu);
    const int d = threadIdx.x * 2;
    float2 f = *(const float2*)&feat[(size_t)row * DIM + d];
    float2 q = *(const float2*)&emb[(size_t)code * DIM + d];
    float2 qst;
    qst.x = f.x + (q.x - f.x);
    qst.y = f.y + (q.y - f.y);
    *(float2*)&qout[(size_t)row * DIM + d] = qst;
    float dx = f.x - qst.x, dy = f.y - qst.y;
    float local = dx * dx + dy * dy;
    #pragma unroll
    for (int off = 32; off; off >>= 1) local += __shfl_down(local, off, 64);
    __shared__ float wsum[4];
    int lane = threadIdx.x & 63, wv = threadIdx.x >> 6;
    if (lane == 0) wsum[wv] = local;
    __syncthreads();
    if (threadIdx.x == 0) {
        atomicAdd(commit, wsum[0] + wsum[1] + wsum[2] + wsum[3]);
        atomicAdd(&csize[code], 1.0f);
        targets[row] = (float)code;
    }
    atomicAdd(&esum[(size_t)code * DIM + d], f.x);
    atomicAdd(&esum[(size_t)code * DIM + d + 1], f.y);
}

// ---------------- kernel 4: new_cs + sum(new_cs) + loss ---------------------
__global__ void newcs_kernel(const float* __restrict__ ema_cs,
                             const float* __restrict__ csize,
                             float* __restrict__ out_cs,
                             float* __restrict__ cs_sum,
                             const float* __restrict__ commit,
                             float* __restrict__ out_loss) {
    int i = blockIdx.x * 256 + threadIdx.x;
    float v = 0.99f * ema_cs[i] + 0.01f * csize[i];
    out_cs[i] = v;
    float s = v;
    #pragma unroll
    for (int off = 32; off; off >>= 1) s += __shfl_down(s, off, 64);
    __shared__ float wsum[4];
    int lane = threadIdx.x & 63, wv = threadIdx.x >> 6;
    if (lane == 0) wsum[wv] = s;
    __syncthreads();
    if (threadIdx.x == 0)
        atomicAdd(cs_sum, wsum[0] + wsum[1] + wsum[2] + wsum[3]);
    if (blockIdx.x == 0 && threadIdx.x == 0)
        out_loss[0] = 0.25f * commit[0] / 8388608.0f;
}

// ---------------- kernel 5: new_w + new_embeddings --------------------------
__global__ void final_kernel(const float* __restrict__ ema_w,
                             const float* __restrict__ esum,
                             const float* __restrict__ new_cs,
                             const float* __restrict__ cs_sum,
                             float* __restrict__ out_w,
                             float* __restrict__ out_emb) {
    size_t i4 = ((size_t)blockIdx.x * 256 + threadIdx.x) * 4;
    int k = (int)(i4 >> 9);
    float S = cs_sum[0] + (float)KCODE * 1e-5f;
    float4 es = *(const float4*)&esum[i4];
    float4 ew = *(const float4*)&ema_w[i4];
    float w0 = 0.99f * ew.x + 0.01f * es.x;
    float w1 = 0.99f * ew.y + 0.01f * es.y;
    float w2 = 0.99f * ew.z + 0.01f * es.z;
    float w3 = 0.99f * ew.w + 0.01f * es.w;
    out_w[i4 + 0] = w0; out_w[i4 + 1] = w1; out_w[i4 + 2] = w2; out_w[i4 + 3] = w3;
    float scale = S / (new_cs[k] + 1e-5f);
    out_emb[i4 + 0] = w0 * scale; out_emb[i4 + 1] = w1 * scale;
    out_emb[i4 + 2] = w2 * scale; out_emb[i4 + 3] = w3 * scale;
}

// ---------------------------------------------------------------------------
extern "C" void kernel_launch(void* const* d_in, const int* in_sizes, int n_in,
                              void* d_out, int out_size, void* d_ws, size_t ws_size,
                              hipStream_t stream) {
    const float* feat   = (const float*)d_in[0];
    const float* emb    = (const float*)d_in[1];
    const float* ema_cs = (const float*)d_in[2];
    const float* ema_w  = (const float*)d_in[3];
    float* out = (float*)d_out;
    char* ws = (char*)d_ws;
    if (ws_size < WS_NEEDED) return;

    unsigned long long* keys = (unsigned long long*)(ws + WS_KEYS);
    float* csize  = (float*)(ws + WS_CSIZE);
    float* commit = (float*)(ws + WS_COMMIT);
    float* cssum  = (float*)(ws + WS_CSSUM);
    float* xnorm  = (float*)(ws + WS_XNORM);
    float* enorm  = (float*)(ws + WS_ENORM);
    float* esum   = (float*)(ws + WS_ESUM);

    hipMemsetAsync(ws + WS_KEYS, 0xFF, (size_t)NROW * 8, stream);
    hipMemsetAsync(ws + WS_CSIZE, 0, WS_CSSUM + 4 - WS_CSIZE, stream);
    hipMemsetAsync(ws + WS_ESUM, 0, (size_t)KCODE * DIM * 4, stream);

    rownorm_kernel<<<NROW / 4, 256, 0, stream>>>(feat, xnorm);
    rownorm_kernel<<<KCODE / 4, 256, 0, stream>>>(emb, enorm);
    argmin_kernel<<<(NROW / RB) * (KCODE / CB), 512, 0, stream>>>(feat, emb, xnorm, enorm, keys);
    gather_kernel<<<NROW, 256, 0, stream>>>(feat, emb, keys, out + Q_OFF, out + T_OFF,
                                            esum, csize, commit);
    newcs_kernel<<<KCODE / 256, 256, 0, stream>>>(ema_cs, csize, out + C_OFF, cssum, commit, out + L_OFF);
    final_kernel<<<KCODE * DIM / 1024, 256, 0, stream>>>(ema_w, esum, out + C_OFF, cssum,
                                                         out + W_OFF, out + E_OFF);
}